// Round 1
// baseline (226.858 us; speedup 1.0000x reference)
//
#include <hip/hip_runtime.h>

#define K_CODES 1024
#define DIM     256
#define NROWS   65536      // 64*32*32
#define BM      128        // z-rows per block
#define BN      64         // codes per chunk
#define NCHUNK  (K_CODES / BN)   // 16
#define THREADS 512

typedef __attribute__((ext_vector_type(8))) short short8;
typedef __attribute__((ext_vector_type(4))) float f32x4;

__device__ __forceinline__ unsigned short f2bf(float f) {
    unsigned int u = __float_as_uint(f);
    u += 0x7fffu + ((u >> 16) & 1u);          // round-to-nearest-even
    return (unsigned short)(u >> 16);
}

// ---- kernel 0: emb f32 -> bf16, row norms, zero loss accumulator ----
__global__ void k_prep(const float* __restrict__ emb,
                       unsigned short* __restrict__ embb,
                       float* __restrict__ normE,
                       float* __restrict__ lossAcc) {
    const int k = blockIdx.x;       // code row
    const int l = threadIdx.x;      // 64 lanes = 1 wave
    float4 v = reinterpret_cast<const float4*>(emb)[k * 64 + l];
    ushort4 b;
    b.x = f2bf(v.x); b.y = f2bf(v.y); b.z = f2bf(v.z); b.w = f2bf(v.w);
    reinterpret_cast<ushort4*>(embb)[k * 64 + l] = b;
    float s = v.x*v.x + v.y*v.y + v.z*v.z + v.w*v.w;
    #pragma unroll
    for (int m = 1; m < 64; m <<= 1) s += __shfl_xor(s, m, 64);
    if (l == 0) normE[k] = s;
    if (k == 0 && l == 0) *lossAcc = 0.f;
}

// ---- kernel 1: distances via bf16 MFMA, argmin, gather, loss partials ----
__launch_bounds__(THREADS, 1)
__global__ void k_main(const float* __restrict__ z,
                       const unsigned short* __restrict__ embb,
                       const float* __restrict__ normE,
                       const float* __restrict__ emb,
                       float* __restrict__ out,
                       float* __restrict__ lossAcc) {
    __shared__ unsigned short zt[BM * DIM];       // 64 KB, XOR-swizzled
    __shared__ unsigned short et[2][BN * DIM];    // 2 x 32 KB, XOR-swizzled
    __shared__ float znorm[BM];
    __shared__ int   sidx[BM];
    __shared__ float sval[BM];

    const int tid  = threadIdx.x;
    const int lane = tid & 63;
    const int w    = tid >> 6;                    // wave 0..7 -> rows [w*16, w*16+16)
    const long brow = (long)blockIdx.x * BM;

    // ---- stage Z: 128 rows x 256 f32 -> bf16 LDS + f32 row norms ----
    #pragma unroll
    for (int i = 0; i < 8; ++i) {
        const int row = (tid >> 5) + i * 16;      // 0..127
        const int cg  = tid & 31;                 // 16B group within row
        const float4* src = reinterpret_cast<const float4*>(z + (brow + row) * DIM + cg * 8);
        float4 a = src[0];
        float4 b = src[1];
        float s = a.x*a.x + a.y*a.y + a.z*a.z + a.w*a.w
                + b.x*b.x + b.y*b.y + b.z*b.z + b.w*b.w;
        #pragma unroll
        for (int m = 1; m < 32; m <<= 1) s += __shfl_xor(s, m, 64);  // 32 lanes share a row
        if (cg == 0) znorm[row] = s;
        short8 sv;
        sv[0]=(short)f2bf(a.x); sv[1]=(short)f2bf(a.y); sv[2]=(short)f2bf(a.z); sv[3]=(short)f2bf(a.w);
        sv[4]=(short)f2bf(b.x); sv[5]=(short)f2bf(b.y); sv[6]=(short)f2bf(b.z); sv[7]=(short)f2bf(b.w);
        unsigned int byte = ((unsigned int)(row * 512 + cg * 16)) ^ (((unsigned int)row & 7u) << 4);
        *reinterpret_cast<short8*>(reinterpret_cast<char*>(zt) + byte) = sv;
    }

    auto eload = [&](int c, int j) -> short8 {
        const int row = (tid >> 5) + j * 16;
        const int cg  = tid & 31;
        return *reinterpret_cast<const short8*>(embb + (long)(c * BN + row) * DIM + cg * 8);
    };
    auto ewrite = [&](int buf, int j, short8 v) {
        const int row = (tid >> 5) + j * 16;
        const int cg  = tid & 31;
        unsigned int byte = ((unsigned int)(row * 512 + cg * 16)) ^ (((unsigned int)row & 7u) << 4);
        *reinterpret_cast<short8*>(reinterpret_cast<char*>(et[buf]) + byte) = v;
    };

    // prologue: stage E chunk 0
    {
        short8 e0 = eload(0, 0), e1 = eload(0, 1), e2 = eload(0, 2), e3 = eload(0, 3);
        ewrite(0, 0, e0); ewrite(0, 1, e1); ewrite(0, 2, e2); ewrite(0, 3, e3);
    }
    __syncthreads();   // covers zt writes + et[0] writes

    // preload A fragments (constant across chunks): lane holds Z[l&15][(l>>4)*8 + j]
    short8 afrag[8];
    {
        const int row = w * 16 + (lane & 15);
        const unsigned int swz = (((unsigned int)row & 7u) << 4);
        const unsigned int kb  = ((unsigned int)(lane >> 4)) * 16u;
        #pragma unroll
        for (int ks = 0; ks < 8; ++ks) {
            unsigned int byte = ((unsigned int)(row * 512) + (unsigned int)ks * 64u + kb) ^ swz;
            afrag[ks] = *reinterpret_cast<const short8*>(reinterpret_cast<const char*>(zt) + byte);
        }
    }

    float rmin[4] = {1e30f, 1e30f, 1e30f, 1e30f};
    int   ridx[4] = {0, 0, 0, 0};
    int cur = 0;

    for (int c = 0; c < NCHUNK; ++c) {
        // issue next chunk's global loads early (T14: hide HBM/L2 latency under MFMA)
        short8 p0, p1, p2, p3;
        if (c + 1 < NCHUNK) {
            p0 = eload(c + 1, 0); p1 = eload(c + 1, 1);
            p2 = eload(c + 1, 2); p3 = eload(c + 1, 3);
        }

        const int cb = c * BN + (lane & 15);
        float ne0 = normE[cb];
        float ne1 = normE[cb + 16];
        float ne2 = normE[cb + 32];
        float ne3 = normE[cb + 48];

        f32x4 acc[4] = {{0.f,0.f,0.f,0.f},{0.f,0.f,0.f,0.f},{0.f,0.f,0.f,0.f},{0.f,0.f,0.f,0.f}};
        const unsigned int kb = ((unsigned int)(lane >> 4)) * 16u;
        const int br = lane & 15;
        #pragma unroll
        for (int ks = 0; ks < 8; ++ks) {
            #pragma unroll
            for (int nt = 0; nt < 4; ++nt) {
                const int row = nt * 16 + br;
                unsigned int byte = ((unsigned int)(row * 512) + (unsigned int)ks * 64u + kb)
                                    ^ (((unsigned int)row & 7u) << 4);
                short8 bf = *reinterpret_cast<const short8*>(reinterpret_cast<const char*>(et[cur]) + byte);
                acc[nt] = __builtin_amdgcn_mfma_f32_16x16x32_bf16(afrag[ks], bf, acc[nt], 0, 0, 0);
            }
        }

        // scores: dist - ||z||^2 = normE - 2*dot ; per-row argmin
        // C/D layout: col = lane&15, row = (lane>>4)*4 + reg
        #pragma unroll
        for (int r = 0; r < 4; ++r) {
            float v0 = fmaf(-2.f, acc[0][r], ne0);
            float v1 = fmaf(-2.f, acc[1][r], ne1);
            float v2 = fmaf(-2.f, acc[2][r], ne2);
            float v3 = fmaf(-2.f, acc[3][r], ne3);
            float bv = v0; int bi = cb;
            if (v1 < bv) { bv = v1; bi = cb + 16; }   // strict <: first-index tie-break
            if (v2 < bv) { bv = v2; bi = cb + 32; }
            if (v3 < bv) { bv = v3; bi = cb + 48; }
            #pragma unroll
            for (int m = 1; m < 16; m <<= 1) {        // reduce over the 16 col-lanes
                float ov = __shfl_xor(bv, m, 64);
                int   oi = __shfl_xor(bi, m, 64);
                if (ov < bv || (ov == bv && oi < bi)) { bv = ov; bi = oi; }
            }
            if (bv < rmin[r]) { rmin[r] = bv; ridx[r] = bi; }  // chunk idx increases: strict <
        }

        if (c + 1 < NCHUNK) {
            ewrite(cur ^ 1, 0, p0); ewrite(cur ^ 1, 1, p1);
            ewrite(cur ^ 1, 2, p2); ewrite(cur ^ 1, 3, p3);
        }
        __syncthreads();
        cur ^= 1;
    }

    // publish per-row (idx, minscore) to LDS
    {
        const int g = lane >> 4;
        #pragma unroll
        for (int r = 0; r < 4; ++r) {
            if ((lane & 15) == r) {
                sidx[w * 16 + g * 4 + r] = ridx[r];
                sval[w * 16 + g * 4 + r] = rmin[r];
            }
        }
    }
    __syncthreads();

    // gather codebook rows (exact f32) -> out ; 4 threads per row
    {
        const int row  = tid >> 2;
        const int q    = tid & 3;
        const int code = sidx[row];
        const float4* src = reinterpret_cast<const float4*>(emb + (long)code * DIM + q * 64);
        float4* dst = reinterpret_cast<float4*>(out + (brow + row) * DIM + q * 64);
        #pragma unroll
        for (int j = 0; j < 16; ++j) dst[j] = src[j];
    }

    // loss partial: sum over rows of (||z||^2 + minscore) = sum ||z - q||^2
    float lp = 0.f;
    if (tid < BM) lp = znorm[tid] + sval[tid];
    #pragma unroll
    for (int m = 1; m < 64; m <<= 1) lp += __shfl_xor(lp, m, 64);
    if (lane == 0 && w < 2) atomicAdd(lossAcc, lp);
}

// ---- kernel 2: finalize losses ----
__global__ void k_loss(const float* __restrict__ lossAcc, float* __restrict__ out2) {
    float loss = 0.5f * lossAcc[0] * (1.f / 16777216.f);   // 0.5 * mean over N*D
    out2[0] = loss;
    out2[1] = loss;
}

extern "C" void kernel_launch(void* const* d_in, const int* in_sizes, int n_in,
                              void* d_out, int out_size, void* d_ws, size_t ws_size,
                              hipStream_t stream) {
    const float* z   = (const float*)d_in[0];
    const float* emb = (const float*)d_in[1];
    float* out = (float*)d_out;
    char*  ws  = (char*)d_ws;
    float* lossAcc       = (float*)ws;                      // 4 B
    float* normE         = (float*)(ws + 256);              // 4 KB
    unsigned short* embb = (unsigned short*)(ws + 256 + 4096); // 512 KB, 16B-aligned

    k_prep<<<K_CODES, 64, 0, stream>>>(emb, embb, normE, lossAcc);
    k_main<<<NROWS / BM, THREADS, 0, stream>>>(z, embb, normE, emb, out, lossAcc);
    k_loss<<<1, 1, 0, stream>>>(lossAcc, out + (long)NROWS * DIM);
}

// Round 2
// 198.228 us; speedup vs baseline: 1.1444x; 1.1444x over previous
//
#include <hip/hip_runtime.h>

#define K_CODES 1024
#define DIM     256
#define NROWS   65536      // 64*32*32
#define BM      128        // z-rows per block
#define BN      64         // codes per chunk
#define NCHUNK  (K_CODES / BN)   // 16
#define THREADS 512

typedef __attribute__((ext_vector_type(8)))  short short8;
typedef __attribute__((ext_vector_type(16))) float f32x16;

__device__ __forceinline__ unsigned short f2bf(float f) {
    unsigned int u = __float_as_uint(f);
    u += 0x7fffu + ((u >> 16) & 1u);          // round-to-nearest-even
    return (unsigned short)(u >> 16);
}

// ---- kernel 0: emb f32 -> bf16, row norms, zero loss accumulator ----
__global__ void k_prep(const float* __restrict__ emb,
                       unsigned short* __restrict__ embb,
                       float* __restrict__ normE,
                       float* __restrict__ lossAcc) {
    const int k = blockIdx.x;       // code row
    const int l = threadIdx.x;      // 64 lanes = 1 wave
    float4 v = reinterpret_cast<const float4*>(emb)[k * 64 + l];
    ushort4 b;
    b.x = f2bf(v.x); b.y = f2bf(v.y); b.z = f2bf(v.z); b.w = f2bf(v.w);
    reinterpret_cast<ushort4*>(embb)[k * 64 + l] = b;
    float s = v.x*v.x + v.y*v.y + v.z*v.z + v.w*v.w;
    #pragma unroll
    for (int m = 1; m < 64; m <<= 1) s += __shfl_xor(s, m, 64);
    if (l == 0) normE[k] = s;
    if (k == 0 && l == 0) *lossAcc = 0.f;
}

// ---- kernel 1: distances via 32x32x16 bf16 MFMA, argmin, gather, loss ----
__launch_bounds__(THREADS, 1)
__global__ void k_main(const float* __restrict__ z,
                       const unsigned short* __restrict__ embb,
                       const float* __restrict__ normE,
                       const float* __restrict__ emb,
                       float* __restrict__ out,
                       float* __restrict__ lossAcc) {
    __shared__ __align__(16) unsigned short et[2][BN * DIM];  // 2 x 32 KB
    __shared__ float sne[K_CODES];   // 4 KB: ||e||^2
    __shared__ float znorm[BM];
    __shared__ float svalw[8][32];
    __shared__ int   sidxw[8][32];
    __shared__ float sval[BM];
    __shared__ int   sidx[BM];

    const int tid  = threadIdx.x;
    const int lane = tid & 63;
    const int w    = tid >> 6;     // 0..7
    const int wr   = w >> 1;       // row group: rows [wr*32, wr*32+32)
    const int wc   = w & 1;        // col half: cols [wc*32, wc*32+32) of chunk
    const long brow = (long)blockIdx.x * BM;

    // stage ||e||^2 to LDS
    for (int i = tid; i < K_CODES; i += THREADS) sne[i] = normE[i];

    // ---- A fragments: global f32 -> registers -> bf16; exact f32 norms ----
    // 32x32x16 A layout: lane holds A[row = l&31][k = (l>>5)*8 + j]
    short8 afrag[16];
    {
        const int arow = wr * 32 + (lane & 31);
        const float* zrow = z + (brow + arow) * DIM + (lane >> 5) * 8;
        float zn = 0.f;
        #pragma unroll
        for (int ks = 0; ks < 16; ++ks) {
            float4 a = *reinterpret_cast<const float4*>(zrow + ks * 16);
            float4 b = *reinterpret_cast<const float4*>(zrow + ks * 16 + 4);
            zn += a.x*a.x + a.y*a.y + a.z*a.z + a.w*a.w
                + b.x*b.x + b.y*b.y + b.z*b.z + b.w*b.w;
            short8 sv;
            sv[0]=(short)f2bf(a.x); sv[1]=(short)f2bf(a.y); sv[2]=(short)f2bf(a.z); sv[3]=(short)f2bf(a.w);
            sv[4]=(short)f2bf(b.x); sv[5]=(short)f2bf(b.y); sv[6]=(short)f2bf(b.z); sv[7]=(short)f2bf(b.w);
            afrag[ks] = sv;
        }
        zn += __shfl_xor(zn, 32, 64);          // combine the two k-halves
        if (wc == 0 && lane < 32) znorm[wr * 32 + lane] = zn;
    }

    // E-tile staging helpers (tile layout: [code 0..63][k 0..255] bf16, XOR-swizzled)
    auto eload = [&](int c, int j) -> short8 {
        const int col = (tid >> 5) + j * 16;
        const int cg  = tid & 31;
        return *reinterpret_cast<const short8*>(embb + (long)(c * BN + col) * DIM + cg * 8);
    };
    auto ewrite = [&](int buf, int j, short8 v) {
        const int col = (tid >> 5) + j * 16;
        const int cg  = tid & 31;
        unsigned int byte = ((unsigned int)(col * 512 + cg * 16)) ^ (((unsigned int)col & 15u) << 4);
        *reinterpret_cast<short8*>(reinterpret_cast<char*>(et[buf]) + byte) = v;
    };

    // prologue: stage chunk 0
    {
        short8 e0 = eload(0, 0), e1 = eload(0, 1), e2 = eload(0, 2), e3 = eload(0, 3);
        ewrite(0, 0, e0); ewrite(0, 1, e1); ewrite(0, 2, e2); ewrite(0, 3, e3);
    }
    __syncthreads();

    float rmin[16];
    int   ridx[16];
    #pragma unroll
    for (int r = 0; r < 16; ++r) { rmin[r] = 1e30f; ridx[r] = 0; }

    const int bcol = wc * 32 + (lane & 31);
    const unsigned int swz  = ((unsigned int)bcol & 15u) << 4;
    const unsigned int rb   = (unsigned int)bcol * 512u + ((unsigned int)(lane >> 5)) * 16u;
    int cur = 0;

    for (int c = 0; c < NCHUNK; ++c) {
        // T14: issue next chunk's global loads before compute
        short8 p0 = {}, p1 = {}, p2 = {}, p3 = {};
        if (c + 1 < NCHUNK) {
            p0 = eload(c + 1, 0); p1 = eload(c + 1, 1);
            p2 = eload(c + 1, 2); p3 = eload(c + 1, 3);
        }

        const char* base = reinterpret_cast<const char*>(et[cur]);
        f32x16 acc = {0.f,0.f,0.f,0.f,0.f,0.f,0.f,0.f,0.f,0.f,0.f,0.f,0.f,0.f,0.f,0.f};
        #pragma unroll
        for (int ks = 0; ks < 16; ++ks) {
            short8 bf = *reinterpret_cast<const short8*>(base + ((rb + (unsigned)ks * 32u) ^ swz));
            acc = __builtin_amdgcn_mfma_f32_32x32x16_bf16(afrag[ks], bf, acc, 0, 0, 0);
        }

        // score = ||e||^2 - 2 z.e ; per-lane running argmin (col fixed per lane)
        const int   cb = c * BN + bcol;
        const float ne = sne[cb];
        #pragma unroll
        for (int r = 0; r < 16; ++r) {
            float v = fmaf(-2.f, acc[r], ne);
            if (v < rmin[r]) { rmin[r] = v; ridx[r] = cb; }   // strict <: first idx wins
        }

        if (c + 1 < NCHUNK) {
            ewrite(cur ^ 1, 0, p0); ewrite(cur ^ 1, 1, p1);
            ewrite(cur ^ 1, 2, p2); ewrite(cur ^ 1, 3, p3);
        }
        __syncthreads();
        cur ^= 1;
    }

    // ---- one-time cross-lane argmin reduce (over the 32 col-lanes) ----
    // C/D layout: col = lane&31, row32 = (r&3) + 8*(r>>2) + 4*(lane>>5)
    #pragma unroll
    for (int r = 0; r < 16; ++r) {
        float bv = rmin[r]; int bi = ridx[r];
        #pragma unroll
        for (int m = 1; m < 32; m <<= 1) {
            float ov = __shfl_xor(bv, m, 64);
            int   oi = __shfl_xor(bi, m, 64);
            if (ov < bv || (ov == bv && oi < bi)) { bv = ov; bi = oi; }
        }
        if ((lane & 31) == 0) {
            const int row32 = (r & 3) + 8 * (r >> 2) + 4 * (lane >> 5);
            svalw[w][row32] = bv; sidxw[w][row32] = bi;
        }
    }
    __syncthreads();

    // combine the two col-half waves per row group
    if (tid < BM) {
        const int g = tid >> 5, r32 = tid & 31;
        float v0 = svalw[g * 2][r32],     v1 = svalw[g * 2 + 1][r32];
        int   i0 = sidxw[g * 2][r32],     i1 = sidxw[g * 2 + 1][r32];
        if (v1 < v0 || (v1 == v0 && i1 < i0)) { sval[tid] = v1; sidx[tid] = i1; }
        else                                  { sval[tid] = v0; sidx[tid] = i0; }
    }
    __syncthreads();

    // gather codebook rows (exact f32) -> out ; 4 threads per row
    {
        const int row  = tid >> 2;
        const int q    = tid & 3;
        const int code = sidx[row];
        const float4* src = reinterpret_cast<const float4*>(emb + (long)code * DIM + q * 64);
        float4* dst = reinterpret_cast<float4*>(out + (brow + row) * DIM + q * 64);
        #pragma unroll
        for (int j = 0; j < 16; ++j) dst[j] = src[j];
    }

    // loss partial: sum over rows of (||z||^2 + minscore) = sum ||z - q||^2
    float lp = 0.f;
    if (tid < BM) lp = znorm[tid] + sval[tid];
    #pragma unroll
    for (int m = 1; m < 64; m <<= 1) lp += __shfl_xor(lp, m, 64);
    if (lane == 0 && w < 2) atomicAdd(lossAcc, lp);
}

// ---- kernel 2: finalize losses ----
__global__ void k_loss(const float* __restrict__ lossAcc, float* __restrict__ out2) {
    float loss = 0.5f * lossAcc[0] * (1.f / 16777216.f);   // 0.5 * mean over N*D
    out2[0] = loss;
    out2[1] = loss;
}

extern "C" void kernel_launch(void* const* d_in, const int* in_sizes, int n_in,
                              void* d_out, int out_size, void* d_ws, size_t ws_size,
                              hipStream_t stream) {
    const float* z   = (const float*)d_in[0];
    const float* emb = (const float*)d_in[1];
    float* out = (float*)d_out;
    char*  ws  = (char*)d_ws;
    float* lossAcc       = (float*)ws;                      // 4 B
    float* normE         = (float*)(ws + 256);              // 4 KB
    unsigned short* embb = (unsigned short*)(ws + 256 + 4096); // 512 KB, 16B-aligned

    k_prep<<<K_CODES, 64, 0, stream>>>(emb, embb, normE, lossAcc);
    k_main<<<NROWS / BM, THREADS, 0, stream>>>(z, embb, normE, emb, out, lossAcc);
    k_loss<<<1, 1, 0, stream>>>(lossAcc, out + (long)NROWS * DIM);
}